// Round 8
// baseline (224.603 us; speedup 1.0000x reference)
//
#include <hip/hip_runtime.h>
#include <hip/hip_bf16.h>

// EdgeEncoder — fp32 inputs, algebraically folded attention:
//   k[i,j] = kbase[j] + W2k @ hid[i,j],   W2k = Wk @ W2
//   score  = q.kbase[j] + qw[i,hd].hid[i,j]
//   ctx    = sum_j attn*vbase[j] + W2v @ (sum_j attn*hid[i,j])
//   out    = PF[i] + PW2 @ attn_out,  PF = PW1@feats+pb (precomputed in d_out)
//
// R8: all query-independent matvecs moved to setup: q (QB fp32 ws) and PF
// (stored in d_out — setup rewrites every element each call before main
// reads it). Main keeps R7's Q=4/wave skeleton minus S1/S2/S9-first-half;
// q consumed via wave-uniform scalar loads. total-main gap ~90us is harness
// reset overhead (constant across R2-R7) — not addressable in-kernel.
//
// ws layout (bytes):
//   [0,32K)     W2KT fp32 [e][ch]
//   [32K,64K)   W2VT fp32 [e][ch]
//   [64K,96K)   OWB  u32  [c][mw]     out_w bf16-pairs
//   [96K,128K)  PW2B u32  [c][mw2]    proj_w cols 128..255 bf16-pairs
//   [128K,+2M)  KBt  u32  [s][cw][j]  kbase bf16-pairs, j fastest
//   [+2M,+4M)   VB   u32  [s][j][cw]  vbase, cw fastest
//   [+4M,+8M)   QB   fp32 [i][128]    q rows
//   total 128K + 8M = 8.5 MB

typedef unsigned int u32;
#define SCALE 0.17677669529663689f   // 1/sqrt(32)

__device__ __forceinline__ float bl(u32 u){ union{u32 x; float f;} c; c.x = u << 16; return c.f; }
__device__ __forceinline__ float bh(u32 u){ union{u32 x; float f;} c; c.x = u & 0xffff0000u; return c.f; }
__device__ __forceinline__ u32 pk(float a, float b){
  union{float f; u32 x;} ca, cb; ca.f = a; cb.f = b;
  u32 ua = (ca.x + 0x7fffu + ((ca.x >> 16) & 1u)) >> 16;   // RNE fp32->bf16
  u32 ub = (cb.x + 0x7fffu + ((cb.x >> 16) & 1u)) >> 16;
  return ua | (ub << 16);
}
__device__ __forceinline__ float dot8(uint4 u, float4 f0, float4 f1, float acc){
  acc = fmaf(bl(u.x), f0.x, acc); acc = fmaf(bh(u.x), f0.y, acc);
  acc = fmaf(bl(u.y), f0.z, acc); acc = fmaf(bh(u.y), f0.w, acc);
  acc = fmaf(bl(u.z), f1.x, acc); acc = fmaf(bh(u.z), f1.y, acc);
  acc = fmaf(bl(u.w), f1.z, acc); acc = fmaf(bh(u.w), f1.w, acc);
  return acc;
}
__device__ __forceinline__ void wsync(){
  __builtin_amdgcn_s_waitcnt(0xC07F);   // lgkmcnt(0)
  __builtin_amdgcn_wave_barrier();
}

// ---------------- kernel 1: setup -------------------------------------------
// grid 1060 x 256:
//   b < 1024 : per-scene mats. s=b>>3, mat=(b>>1)&3 (0=K,1=V,2=Q,3=PF), hlf=b&1
//   b < 1056 : W2 folds (fp32)
//   b < 1060 : bf16 packing OWB + PW2B
__global__ __launch_bounds__(256, 2) void ee_setup(
    const float* __restrict__ nf, const float* __restrict__ b2,
    const float* __restrict__ ipw, const float* __restrict__ ipb,
    const float* __restrict__ w2,
    const float* __restrict__ pw, const float* __restrict__ pb,
    const float* __restrict__ ow,
    float* __restrict__ W2KT, float* __restrict__ W2VT,
    u32* __restrict__ OWB, u32* __restrict__ PW2B,
    u32* __restrict__ KBt, u32* __restrict__ VB,
    float* __restrict__ QB, float* __restrict__ PF)
{
  const int tid = threadIdx.x, b = blockIdx.x;
  const int cg = tid >> 6, l = tid & 63;

  if (b >= 1056) {             // ---- weight packing, coalesced ----
    const float2* ow2 = (const float2*)ow;
    const float2* pw2 = (const float2*)pw;
    for (int k = 0; k < 16; ++k) {
      int i = (b - 1056) * 4096 + k * 256 + tid;      // 0..16383
      if (i < 8192) { float2 f = ow2[i]; OWB[i] = pk(f.x, f.y); }
      else {
        int m = i - 8192; int c = m >> 6, mw = m & 63;
        float2 f = pw2[c * 128 + 64 + mw];            // cols 128..255
        PW2B[m] = pk(f.x, f.y);
      }
    }
    return;
  }
  if (b >= 1024) {             // ---- W2 folds: W2x[ch][e] = Wk/Wv @ W2 ----
    int t = (b - 1024) * 4 + cg;
    int kv = t & 1, e = t >> 1;
    int c0 = 2 * l;
    const float4* rp = (const float4*)ipw + (size_t)(128 + kv * 128 + c0) * 32;
    const float* w2e = w2 + __builtin_amdgcn_readfirstlane(e);
    float a0 = 0.f, a1 = 0.f;
    #pragma unroll 8
    for (int c4 = 0; c4 < 32; ++c4) {
      float4 wa = rp[c4], wb = rp[32 + c4];
      float x0 = w2e[(4 * c4 + 0) * 64];
      float x1 = w2e[(4 * c4 + 1) * 64];
      float x2 = w2e[(4 * c4 + 2) * 64];
      float x3 = w2e[(4 * c4 + 3) * 64];
      a0 = fmaf(wa.x, x0, a0); a0 = fmaf(wa.y, x1, a0);
      a0 = fmaf(wa.z, x2, a0); a0 = fmaf(wa.w, x3, a0);
      a1 = fmaf(wb.x, x0, a1); a1 = fmaf(wb.y, x1, a1);
      a1 = fmaf(wb.z, x2, a1); a1 = fmaf(wb.w, x3, a1);
    }
    float* dst = kv ? W2VT : W2KT;
    ((float2*)dst)[e * 64 + l] = make_float2(a0, a1);
    return;
  }

  // ---- per-scene mats: K,V (bf16 bases) / Q,PF (fp32 rows) ----
  const int s = b >> 3, mat = (b >> 1) & 3, hlf = b & 1;
  __shared__ __align__(16) u32 fbS[64][68];   // feats (+b2 for K/V) bf16-pairs
  __shared__ __align__(16) u32 xS[64][68];    // transpose buffer (u32 / float)
  const float2* nf2 = (const float2*)nf;
  const float2* b22 = (const float2*)b2;

  for (int idx = tid; idx < 4096; idx += 256) {
    int j = idx >> 6, mw = idx & 63;
    float2 f = nf2[((s << 6) + j) * 64 + mw];
    if (mat < 2) { float2 bb = b22[mw]; f.x += bb.x; f.y += bb.y; }
    fbS[j][mw] = pk(f.x, f.y);
  }
  __syncthreads();

  uint4 fr[16];                      // feats row (lane = ped), read once
  {
    const uint4* frow = (const uint4*)&fbS[l][0];
    #pragma unroll
    for (int k = 0; k < 16; ++k) fr[k] = frow[k];
  }
  const float* wbase = (mat == 3) ? pw : ipw;
  const int rbase = (mat == 0) ? 128 : (mat == 1) ? 256 : 0;
  const int rlen4 = (mat == 3) ? 64 : 32;          // float4 per weight row
  const float* bptr = (mat == 3) ? pb : (ipb + rbase);

  #pragma unroll 1
  for (int p = 0; p < 8; ++p) {
    int c0 = hlf * 64 + cg * 16 + 2 * p;           // wave-uniform
    int row = __builtin_amdgcn_readfirstlane(rbase + c0);
    const float4* w0 = (const float4*)wbase + (size_t)row * rlen4;
    const float4* w1r = w0 + rlen4;
    float a0 = bptr[c0], a1 = bptr[c0 + 1];
    #pragma unroll
    for (int k = 0; k < 16; ++k) {
      uint4 F = fr[k];
      float4 wa = w0[2 * k],  wb = w0[2 * k + 1];
      float4 xa = w1r[2 * k], xb = w1r[2 * k + 1];
      float e0 = bl(F.x), e1 = bh(F.x), e2 = bl(F.y), e3 = bh(F.y);
      float e4 = bl(F.z), e5 = bh(F.z), e6 = bl(F.w), e7 = bh(F.w);
      a0 = fmaf(e0, wa.x, a0); a0 = fmaf(e1, wa.y, a0);
      a0 = fmaf(e2, wa.z, a0); a0 = fmaf(e3, wa.w, a0);
      a0 = fmaf(e4, wb.x, a0); a0 = fmaf(e5, wb.y, a0);
      a0 = fmaf(e6, wb.z, a0); a0 = fmaf(e7, wb.w, a0);
      a1 = fmaf(e0, xa.x, a1); a1 = fmaf(e1, xa.y, a1);
      a1 = fmaf(e2, xa.z, a1); a1 = fmaf(e3, xa.w, a1);
      a1 = fmaf(e4, xb.x, a1); a1 = fmaf(e5, xb.y, a1);
      a1 = fmaf(e6, xb.z, a1); a1 = fmaf(e7, xb.w, a1);
    }
    if (mat == 0) {
      KBt[(((s << 6) + hlf * 32 + cg * 8 + p) << 6) + l] = pk(a0, a1);
    } else if (mat == 1) {
      xS[l][cg * 8 + p] = pk(a0, a1);
    } else {
      float* fx = (float*)xS;
      fx[l * 68 + cg * 16 + 2 * p]     = a0;
      fx[l * 68 + cg * 16 + 2 * p + 1] = a1;
    }
  }
  if (mat == 1) {
    __syncthreads();
    int r = tid >> 2, cb = (tid & 3) * 8;
    #pragma unroll
    for (int k = 0; k < 8; ++k)
      VB[(((s << 6) + r) << 6) + hlf * 32 + cb + k] = xS[r][cb + k];
  } else if (mat >= 2) {
    __syncthreads();
    int r = tid >> 2, g = (tid & 3) * 16;
    const float* fx = (const float*)xS;
    float* dst = (mat == 2) ? QB : PF;
    #pragma unroll
    for (int k = 0; k < 16; ++k)
      dst[((s << 6) + r) * 128 + hlf * 64 + g + k] = fx[r * 68 + g + k];
  }
}

// ---------------- kernel 2: Q=4 queries per wave, wave-synchronous ----------
// grid 512 x 256: b -> s = b>>2, qt = b&3; wave w -> queries qt*16+4w+t.
__global__ __launch_bounds__(256, 2) void ee_main(
    const float* __restrict__ pos,
    const float* __restrict__ w1, const float* __restrict__ b1,
    const float* __restrict__ ob,
    const float* __restrict__ W2KT, const float* __restrict__ W2VT,
    const u32* __restrict__ OWB, const u32* __restrict__ PW2B,
    const u32* __restrict__ KBt, const u32* __restrict__ VB,
    const float* __restrict__ QB,
    float* __restrict__ outp)
{
  __shared__ __align__(16) float pxS[64], pyS[64], w1xS[64], w1yS[64], b1S[64];
  __shared__ __align__(16) float qwS[4][4][4][68];   // qw [w][t][hd][e]
  __shared__ __align__(16) float atS[4][4][4][68];   // at [w][t][hd][j]
  __shared__ __align__(16) float whS[4][4][4][68];   // wh [w][t][hd][e]
  __shared__ __align__(16) float cxS[4][4][132];     // ctx -> ao

  const int tid = threadIdx.x;
  const int s = blockIdx.x >> 2, qt = blockIdx.x & 3;
  const int w = tid >> 6, l = tid & 63;
  const int c0 = 2 * l;

  if (tid < 64) {
    float2 p = ((const float2*)pos)[(s << 6) + tid];
    pxS[tid] = p.x; pyS[tid] = p.y;
    float2 wv = ((const float2*)w1)[tid];
    w1xS[tid] = wv.x; w1yS[tid] = wv.y;
    b1S[tid] = b1[tid];
  }
  __syncthreads();
  // ---- no block barriers past here ----

  const int wq = __builtin_amdgcn_readfirstlane(w);
  int il[4], ig[4];
  const float4* q4[4];
  #pragma unroll
  for (int t = 0; t < 4; ++t) {
    il[t] = qt * 16 + 4 * wq + t;
    ig[t] = (s << 6) + il[t];
    q4[t] = (const float4*)(QB + (size_t)ig[t] * 128);   // uniform -> s_load
  }

  // S4: qw[t][hd][e=l] = q_hd . W2k[:,e]_hd  (W2KT vector rows, q scalar)
  {
    const float4* G4 = (const float4*)W2KT;
    #pragma unroll
    for (int hd = 0; hd < 4; ++hd) {
      float acc[4] = {0.f, 0.f, 0.f, 0.f};
      #pragma unroll
      for (int dq = 0; dq < 8; ++dq) {
        float4 g = G4[l * 32 + hd * 8 + dq];
        #pragma unroll
        for (int t = 0; t < 4; ++t) {
          float4 qf = q4[t][hd * 8 + dq];
          acc[t] = fmaf(g.x, qf.x, acc[t]); acc[t] = fmaf(g.y, qf.y, acc[t]);
          acc[t] = fmaf(g.z, qf.z, acc[t]); acc[t] = fmaf(g.w, qf.w, acc[t]);
        }
      }
      #pragma unroll
      for (int t = 0; t < 4; ++t) qwS[w][t][hd][l] = acc[t];
    }
  }
  wsync();

  // S5: scores + softmax (lane = j; kb vector loads, q scalar)
  float at[4][4];        // [t][hd]
  float pix[4], piy[4];
  {
    float pjx = pxS[l], pjy = pyS[l];
    float rx[4], ry[4];
    #pragma unroll
    for (int t = 0; t < 4; ++t) {
      pix[t] = pxS[il[t]]; piy[t] = pyS[il[t]];      // broadcast reads
      rx[t] = pjx - pix[t]; ry[t] = pjy - piy[t];
    }
    float sc[4][4];
    #pragma unroll
    for (int t = 0; t < 4; ++t)
      #pragma unroll
      for (int hd = 0; hd < 4; ++hd) sc[t][hd] = 0.f;

    const u32* kbp = KBt + (s << 12);
    #pragma unroll 8
    for (int m2 = 0; m2 < 32; ++m2) {
      u32 u0 = kbp[((2 * m2) << 6) + l];
      u32 u1 = kbp[((2 * m2 + 1) << 6) + l];
      const int hd = m2 >> 3;
      float f0 = bl(u0), f1 = bh(u0), f2 = bl(u1), f3 = bh(u1);
      #pragma unroll
      for (int t = 0; t < 4; ++t) {
        float4 qf = q4[t][m2];
        sc[t][hd] = fmaf(f0, qf.x, sc[t][hd]);
        sc[t][hd] = fmaf(f1, qf.y, sc[t][hd]);
        sc[t][hd] = fmaf(f2, qf.z, sc[t][hd]);
        sc[t][hd] = fmaf(f3, qf.w, sc[t][hd]);
      }
    }
    #pragma unroll 2
    for (int eb = 0; eb < 8; ++eb) {
      float4 wx0 = *(const float4*)&w1xS[8 * eb];
      float4 wx1 = *(const float4*)&w1xS[8 * eb + 4];
      float4 wy0 = *(const float4*)&w1yS[8 * eb];
      float4 wy1 = *(const float4*)&w1yS[8 * eb + 4];
      float4 bb0 = *(const float4*)&b1S[8 * eb];
      float4 bb1 = *(const float4*)&b1S[8 * eb + 4];
      #pragma unroll
      for (int t = 0; t < 4; ++t) {
        float h0 = fmaxf(0.f, fmaf(rx[t], wx0.x, fmaf(ry[t], wy0.x, bb0.x)));
        float h1 = fmaxf(0.f, fmaf(rx[t], wx0.y, fmaf(ry[t], wy0.y, bb0.y)));
        float h2 = fmaxf(0.f, fmaf(rx[t], wx0.z, fmaf(ry[t], wy0.z, bb0.z)));
        float h3 = fmaxf(0.f, fmaf(rx[t], wx0.w, fmaf(ry[t], wy0.w, bb0.w)));
        float h4 = fmaxf(0.f, fmaf(rx[t], wx1.x, fmaf(ry[t], wy1.x, bb1.x)));
        float h5 = fmaxf(0.f, fmaf(rx[t], wx1.y, fmaf(ry[t], wy1.y, bb1.y)));
        float h6 = fmaxf(0.f, fmaf(rx[t], wx1.z, fmaf(ry[t], wy1.z, bb1.z)));
        float h7 = fmaxf(0.f, fmaf(rx[t], wx1.w, fmaf(ry[t], wy1.w, bb1.w)));
        #pragma unroll
        for (int hd = 0; hd < 4; ++hd) {
          float4 q0 = *(const float4*)&qwS[w][t][hd][8 * eb];
          float4 q1 = *(const float4*)&qwS[w][t][hd][8 * eb + 4];
          float a = sc[t][hd];
          a = fmaf(q0.x, h0, a); a = fmaf(q0.y, h1, a);
          a = fmaf(q0.z, h2, a); a = fmaf(q0.w, h3, a);
          a = fmaf(q1.x, h4, a); a = fmaf(q1.y, h5, a);
          a = fmaf(q1.z, h6, a); a = fmaf(q1.w, h7, a);
          sc[t][hd] = a;
        }
      }
    }
    #pragma unroll
    for (int t = 0; t < 4; ++t) {
      #pragma unroll
      for (int hd = 0; hd < 4; ++hd) {
        float v = sc[t][hd] * SCALE;
        float m = v;
        #pragma unroll
        for (int off = 32; off > 0; off >>= 1) m = fmaxf(m, __shfl_xor(m, off));
        float p = __expf(v - m);
        float su = p;
        #pragma unroll
        for (int off = 32; off > 0; off >>= 1) su += __shfl_xor(su, off);
#if __has_builtin(__builtin_amdgcn_rcpf)
        at[t][hd] = p * __builtin_amdgcn_rcpf(su);
#else
        at[t][hd] = p / su;
#endif
        atS[w][t][hd][l] = at[t][hd];
      }
    }
  }
  wsync();

  // S6: wh[t][hd][e=l] = sum_j at[t][hd][j]*hid[t][j][e]
  {
    float wx = w1xS[l], wy = w1yS[l], bb = b1S[l];
    float wh[4][4];
    #pragma unroll
    for (int t = 0; t < 4; ++t)
      #pragma unroll
      for (int hd = 0; hd < 4; ++hd) wh[t][hd] = 0.f;
    #pragma unroll 4
    for (int j4 = 0; j4 < 16; ++j4) {
      float4 px = *(const float4*)&pxS[4 * j4];
      float4 py = *(const float4*)&pyS[4 * j4];
      #pragma unroll
      for (int t = 0; t < 4; ++t) {
        float4 a0v = *(const float4*)&atS[w][t][0][4 * j4];
        float4 a1v = *(const float4*)&atS[w][t][1][4 * j4];
        float4 a2v = *(const float4*)&atS[w][t][2][4 * j4];
        float4 a3v = *(const float4*)&atS[w][t][3][4 * j4];
        float h;
        h = fmaxf(0.f, fmaf(px.x - pix[t], wx, fmaf(py.x - piy[t], wy, bb)));
        wh[t][0] = fmaf(a0v.x, h, wh[t][0]); wh[t][1] = fmaf(a1v.x, h, wh[t][1]);
        wh[t][2] = fmaf(a2v.x, h, wh[t][2]); wh[t][3] = fmaf(a3v.x, h, wh[t][3]);
        h = fmaxf(0.f, fmaf(px.y - pix[t], wx, fmaf(py.y - piy[t], wy, bb)));
        wh[t][0] = fmaf(a0v.y, h, wh[t][0]); wh[t][1] = fmaf(a1v.y, h, wh[t][1]);
        wh[t][2] = fmaf(a2v.y, h, wh[t][2]); wh[t][3] = fmaf(a3v.y, h, wh[t][3]);
        h = fmaxf(0.f, fmaf(px.z - pix[t], wx, fmaf(py.z - piy[t], wy, bb)));
        wh[t][0] = fmaf(a0v.z, h, wh[t][0]); wh[t][1] = fmaf(a1v.z, h, wh[t][1]);
        wh[t][2] = fmaf(a2v.z, h, wh[t][2]); wh[t][3] = fmaf(a3v.z, h, wh[t][3]);
        h = fmaxf(0.f, fmaf(px.w - pix[t], wx, fmaf(py.w - piy[t], wy, bb)));
        wh[t][0] = fmaf(a0v.w, h, wh[t][0]); wh[t][1] = fmaf(a1v.w, h, wh[t][1]);
        wh[t][2] = fmaf(a2v.w, h, wh[t][2]); wh[t][3] = fmaf(a3v.w, h, wh[t][3]);
      }
    }
    #pragma unroll
    for (int t = 0; t < 4; ++t)
      #pragma unroll
      for (int hd = 0; hd < 4; ++hd) whS[w][t][hd][l] = wh[t][hd];
  }
  wsync();

  // S7: ctx (lane -> channels c0,c0+1; head = l>>4)
  {
    const int hd = l >> 4;
    float cx0[4] = {0,0,0,0}, cx1[4] = {0,0,0,0};
    const float2* V2 = (const float2*)W2VT;
    const u32* vbp = VB + (s << 12);
    #pragma unroll 4
    for (int n4 = 0; n4 < 16; ++n4) {
      float2 g0 = V2[((4 * n4 + 0) << 6) + l];
      float2 g1 = V2[((4 * n4 + 1) << 6) + l];
      float2 g2 = V2[((4 * n4 + 2) << 6) + l];
      float2 g3 = V2[((4 * n4 + 3) << 6) + l];
      u32 v0 = vbp[((4 * n4 + 0) << 6) + l];
      u32 v1 = vbp[((4 * n4 + 1) << 6) + l];
      u32 v2 = vbp[((4 * n4 + 2) << 6) + l];
      u32 v3 = vbp[((4 * n4 + 3) << 6) + l];
      #pragma unroll
      for (int t = 0; t < 4; ++t) {
        float4 whv = *(const float4*)&whS[w][t][hd][4 * n4];
        float4 atv = *(const float4*)&atS[w][t][hd][4 * n4];
        float a0 = cx0[t], a1 = cx1[t];
        a0 = fmaf(whv.x, g0.x, a0); a1 = fmaf(whv.x, g0.y, a1);
        a0 = fmaf(atv.x, bl(v0), a0); a1 = fmaf(atv.x, bh(v0), a1);
        a0 = fmaf(whv.y, g1.x, a0); a1 = fmaf(whv.y, g1.y, a1);
        a0 = fmaf(atv.y, bl(v1), a0); a1 = fmaf(atv.y, bh(v1), a1);
        a0 = fmaf(whv.z, g2.x, a0); a1 = fmaf(whv.z, g2.y, a1);
        a0 = fmaf(atv.z, bl(v2), a0); a1 = fmaf(atv.z, bh(v2), a1);
        a0 = fmaf(whv.w, g3.x, a0); a1 = fmaf(whv.w, g3.y, a1);
        a0 = fmaf(atv.w, bl(v3), a0); a1 = fmaf(atv.w, bh(v3), a1);
        cx0[t] = a0; cx1[t] = a1;
      }
    }
    #pragma unroll
    for (int t = 0; t < 4; ++t)
      *(float2*)&cxS[w][t][c0] = make_float2(cx0[t], cx1[t]);
  }
  wsync();

  // S8: attn_out = out_w @ ctx + out_b
  {
    float2 b = ((const float2*)ob)[l];
    float a0[4], a1[4];
    #pragma unroll
    for (int t = 0; t < 4; ++t) { a0[t] = b.x; a1[t] = b.y; }
    const uint4* W4 = (const uint4*)OWB;
    #pragma unroll 4
    for (int m8 = 0; m8 < 16; ++m8) {
      uint4 ua = W4[c0 * 16 + m8];
      uint4 ub = W4[(c0 + 1) * 16 + m8];
      #pragma unroll
      for (int t = 0; t < 4; ++t) {
        float4 f0 = *(const float4*)&cxS[w][t][8 * m8];
        float4 f1 = *(const float4*)&cxS[w][t][8 * m8 + 4];
        a0[t] = dot8(ua, f0, f1, a0[t]);
        a1[t] = dot8(ub, f0, f1, a1[t]);
      }
    }
    wsync();   // all ctx reads complete before overwrite
    #pragma unroll
    for (int t = 0; t < 4; ++t)
      *(float2*)&cxS[w][t][c0] = make_float2(a0[t], a1[t]);   // ao over ctx
  }
  wsync();

  // S9: out = PF[i] + PW2 @ attn_out   (PF precomputed in d_out by setup)
  {
    float a0[4], a1[4];
    #pragma unroll
    for (int t = 0; t < 4; ++t) {
      float2 pf = ((const float2*)outp)[ig[t] * 64 + l];
      a0[t] = pf.x; a1[t] = pf.y;
    }
    const uint4* W4 = (const uint4*)PW2B;
    #pragma unroll 4
    for (int m8 = 0; m8 < 16; ++m8) {
      uint4 ua = W4[c0 * 16 + m8];
      uint4 ub = W4[(c0 + 1) * 16 + m8];
      #pragma unroll
      for (int t = 0; t < 4; ++t) {
        float4 f0 = *(const float4*)&cxS[w][t][8 * m8];
        float4 f1 = *(const float4*)&cxS[w][t][8 * m8 + 4];
        a0[t] = dot8(ua, f0, f1, a0[t]);
        a1[t] = dot8(ub, f0, f1, a1[t]);
      }
    }
    #pragma unroll
    for (int t = 0; t < 4; ++t)
      ((float2*)outp)[ig[t] * 64 + l] = make_float2(a0[t], a1[t]);
  }
}

extern "C" void kernel_launch(void* const* d_in, const int* in_sizes, int n_in,
                              void* d_out, int out_size, void* d_ws, size_t ws_size,
                              hipStream_t stream) {
  (void)in_sizes; (void)n_in; (void)out_size; (void)ws_size;
  const float* nf  = (const float*)d_in[0];
  const float* pos = (const float*)d_in[1];
  const float* w1  = (const float*)d_in[2];
  const float* b1  = (const float*)d_in[3];
  const float* w2  = (const float*)d_in[4];
  const float* b2  = (const float*)d_in[5];
  const float* ipw = (const float*)d_in[6];
  const float* ipb = (const float*)d_in[7];
  const float* ow  = (const float*)d_in[8];
  const float* ob  = (const float*)d_in[9];
  const float* pw  = (const float*)d_in[10];
  const float* pb  = (const float*)d_in[11];

  char* ws = (char*)d_ws;
  float* W2KT = (float*)(ws);
  float* W2VT = (float*)(ws + (32 << 10));
  u32* OWB   = (u32*)(ws + (64 << 10));
  u32* PW2B  = (u32*)(ws + (96 << 10));
  u32* KBt   = (u32*)(ws + (128 << 10));
  u32* VB    = (u32*)(ws + (128 << 10) + (128 * 4096 * 4));
  float* QB  = (float*)(ws + (128 << 10) + (2 * 128 * 4096 * 4));
  float* PF  = (float*)d_out;

  ee_setup<<<dim3(1060), dim3(256), 0, stream>>>(nf, b2, ipw, ipb, w2, pw, pb, ow,
                                                 W2KT, W2VT, OWB, PW2B,
                                                 KBt, VB, QB, PF);
  ee_main<<<dim3(512), dim3(256), 0, stream>>>(pos, w1, b1, ob,
                                               W2KT, W2VT, OWB, PW2B,
                                               KBt, VB, QB, (float*)d_out);
}

// Round 9
// 222.038 us; speedup vs baseline: 1.0116x; 1.0116x over previous
//
#include <hip/hip_runtime.h>
#include <hip/hip_bf16.h>

// EdgeEncoder — fp32 inputs, algebraically folded attention:
//   k[i,j] = kbase[j] + W2k @ hid[i,j],   W2k = Wk @ W2
//   score  = q.kbase[j] + qw[i,hd].hid[i,j]
//   ctx    = sum_j attn*vbase[j] + W2v @ (sum_j attn*hid[i,j])
//
// R9: DS-pipe diet (R8 proved main is DS/latency-bound, not VALU-bound):
// q/ctx/ao live in registers and are broadcast within the wave via
// v_readlane (VALU) instead of LDS round-trips; feats via wave-uniform
// scalar (SMEM) loads; qw/wh overlay one LDS array; W2KT transposed for
// coalesced S4 reads. LDS 70.6KB -> 18.7KB, Q=2/wave x 1024 blocks ->
// 16 waves/CU. Setup = R7's proven version (+W2KT transpose).
// total-main gap ~90us is harness reset overhead — not addressable here.
//
// ws layout (bytes):
//   [0,32K)     W2KT fp32 [ch][e]   (Wk@W2, TRANSPOSED: e fastest)
//   [32K,64K)   W2VT fp32 [e][ch]
//   [64K,96K)   WQB  u32  [c][mw]   Wq bf16-pairs
//   [96K,128K)  OWB  u32  [c][mw]   out_w
//   [128K,192K) PWB  u32  [c][mw]   proj_w
//   [192K,+2M)  KBt  u32  [s][cw][j]  kbase bf16-pairs, j fastest
//   [+2M,+4M)   VB   u32  [s][j][cw]  vbase, cw fastest

typedef unsigned int u32;
#define SCALE 0.17677669529663689f   // 1/sqrt(32)

__device__ __forceinline__ float bl(u32 u){ union{u32 x; float f;} c; c.x = u << 16; return c.f; }
__device__ __forceinline__ float bh(u32 u){ union{u32 x; float f;} c; c.x = u & 0xffff0000u; return c.f; }
__device__ __forceinline__ u32 pk(float a, float b){
  union{float f; u32 x;} ca, cb; ca.f = a; cb.f = b;
  u32 ua = (ca.x + 0x7fffu + ((ca.x >> 16) & 1u)) >> 16;   // RNE fp32->bf16
  u32 ub = (cb.x + 0x7fffu + ((cb.x >> 16) & 1u)) >> 16;
  return ua | (ub << 16);
}
__device__ __forceinline__ float dot8(uint4 u, float4 f0, float4 f1, float acc){
  acc = fmaf(bl(u.x), f0.x, acc); acc = fmaf(bh(u.x), f0.y, acc);
  acc = fmaf(bl(u.y), f0.z, acc); acc = fmaf(bh(u.y), f0.w, acc);
  acc = fmaf(bl(u.z), f1.x, acc); acc = fmaf(bh(u.z), f1.y, acc);
  acc = fmaf(bl(u.w), f1.z, acc); acc = fmaf(bh(u.w), f1.w, acc);
  return acc;
}
__device__ __forceinline__ float dot8v(uint4 u, const float* x, float acc){
  acc = fmaf(bl(u.x), x[0], acc); acc = fmaf(bh(u.x), x[1], acc);
  acc = fmaf(bl(u.y), x[2], acc); acc = fmaf(bh(u.y), x[3], acc);
  acc = fmaf(bl(u.z), x[4], acc); acc = fmaf(bh(u.z), x[5], acc);
  acc = fmaf(bl(u.w), x[6], acc); acc = fmaf(bh(u.w), x[7], acc);
  return acc;
}
__device__ __forceinline__ float rl(float v, int lane){
  return __int_as_float(__builtin_amdgcn_readlane(__float_as_int(v), lane));
}
// broadcast 8 consecutive channels (8b..8b+7) from per-lane channel regs
#define RL8(dst, r0, r1, base4) \
  dst[0] = rl(r0, (base4));     dst[1] = rl(r1, (base4)); \
  dst[2] = rl(r0, (base4) + 1); dst[3] = rl(r1, (base4) + 1); \
  dst[4] = rl(r0, (base4) + 2); dst[5] = rl(r1, (base4) + 2); \
  dst[6] = rl(r0, (base4) + 3); dst[7] = rl(r1, (base4) + 3);
__device__ __forceinline__ void wsync(){
  __builtin_amdgcn_s_waitcnt(0xC07F);   // lgkmcnt(0)
  __builtin_amdgcn_wave_barrier();
}

// ---------------- kernel 1: setup (R7-proven; W2KT now transposed) ----------
__global__ __launch_bounds__(256, 2) void ee_setup(
    const float* __restrict__ nf, const float* __restrict__ b2,
    const float* __restrict__ ipw, const float* __restrict__ ipb,
    const float* __restrict__ w2,
    const float* __restrict__ ow, const float* __restrict__ pw,
    float* __restrict__ W2KT, float* __restrict__ W2VT,
    u32* __restrict__ WQB, u32* __restrict__ OWB, u32* __restrict__ PWB,
    u32* __restrict__ KBt, u32* __restrict__ VB)
{
  const int tid = threadIdx.x, b = blockIdx.x;
  const int cg = tid >> 6, l = tid & 63;
  const float2* ipw2 = (const float2*)ipw;
  const float2* ow2  = (const float2*)ow;
  const float2* pw2  = (const float2*)pw;

  if (b >= 544) {              // ---- weight packing, fully coalesced ----
    for (int k = 0; k < 16; ++k) {
      int i = (b - 544) * 4096 + k * 256 + tid;    // 0..32767
      if (i < 8192)       { float2 f = ipw2[i];        WQB[i]        = pk(f.x, f.y); }
      else if (i < 16384) { float2 f = ow2[i - 8192];  OWB[i - 8192] = pk(f.x, f.y); }
      else                { float2 f = pw2[i - 16384]; PWB[i - 16384]= pk(f.x, f.y); }
    }
    return;
  }
  if (b >= 512) {              // ---- W2 folds: W2x[ch][e] = Wk/Wv @ W2 ----
    int t = (b - 512) * 4 + cg;
    int kv = t & 1, e = t >> 1;
    int c0 = 2 * l;
    const float4* rp = (const float4*)ipw + (size_t)(128 + kv * 128 + c0) * 32;
    const float* w2e = w2 + __builtin_amdgcn_readfirstlane(e);
    float a0 = 0.f, a1 = 0.f;
    #pragma unroll 8
    for (int c4 = 0; c4 < 32; ++c4) {
      float4 wa = rp[c4], wb = rp[32 + c4];
      float x0 = w2e[(4 * c4 + 0) * 64];
      float x1 = w2e[(4 * c4 + 1) * 64];
      float x2 = w2e[(4 * c4 + 2) * 64];
      float x3 = w2e[(4 * c4 + 3) * 64];
      a0 = fmaf(wa.x, x0, a0); a0 = fmaf(wa.y, x1, a0);
      a0 = fmaf(wa.z, x2, a0); a0 = fmaf(wa.w, x3, a0);
      a1 = fmaf(wb.x, x0, a1); a1 = fmaf(wb.y, x1, a1);
      a1 = fmaf(wb.z, x2, a1); a1 = fmaf(wb.w, x3, a1);
    }
    if (kv) ((float2*)W2VT)[e * 64 + l] = make_float2(a0, a1);
    else {                       // transposed: [ch][e], e fastest
      W2KT[(2 * l) * 64 + e]     = a0;
      W2KT[(2 * l + 1) * 64 + e] = a1;
    }
    return;
  }

  const int s = b >> 2, kv = (b >> 1) & 1, hlf = b & 1;
  __shared__ __align__(16) u32 fbS[64][68];
  __shared__ u32 vtS[64][33];
  const float2* nf2 = (const float2*)nf;
  const float2* b22 = (const float2*)b2;

  for (int idx = tid; idx < 4096; idx += 256) {
    int j = idx >> 6, mw = idx & 63;
    float2 f = nf2[((s << 6) + j) * 64 + mw];
    float2 bb = b22[mw];
    fbS[j][mw] = pk(f.x + bb.x, f.y + bb.y);
  }
  __syncthreads();

  uint4 fr[16];
  {
    const uint4* frow = (const uint4*)&fbS[l][0];
    #pragma unroll
    for (int k = 0; k < 16; ++k) fr[k] = frow[k];
  }
  #pragma unroll 1
  for (int p = 0; p < 8; ++p) {
    int c0 = hlf * 64 + cg * 16 + 2 * p;
    int r0 = 128 + kv * 128 + c0;
    const float4* w0 = (const float4*)ipw +
                       (size_t)__builtin_amdgcn_readfirstlane(r0) * 32;
    const float4* w1r = w0 + 32;
    float a0 = ipb[r0], a1 = ipb[r0 + 1];
    #pragma unroll
    for (int k = 0; k < 16; ++k) {
      uint4 F = fr[k];
      float4 wa = w0[2 * k],  wb = w0[2 * k + 1];
      float4 xa = w1r[2 * k], xb = w1r[2 * k + 1];
      float e0 = bl(F.x), e1 = bh(F.x), e2 = bl(F.y), e3 = bh(F.y);
      float e4 = bl(F.z), e5 = bh(F.z), e6 = bl(F.w), e7 = bh(F.w);
      a0 = fmaf(e0, wa.x, a0); a0 = fmaf(e1, wa.y, a0);
      a0 = fmaf(e2, wa.z, a0); a0 = fmaf(e3, wa.w, a0);
      a0 = fmaf(e4, wb.x, a0); a0 = fmaf(e5, wb.y, a0);
      a0 = fmaf(e6, wb.z, a0); a0 = fmaf(e7, wb.w, a0);
      a1 = fmaf(e0, xa.x, a1); a1 = fmaf(e1, xa.y, a1);
      a1 = fmaf(e2, xa.z, a1); a1 = fmaf(e3, xa.w, a1);
      a1 = fmaf(e4, xb.x, a1); a1 = fmaf(e5, xb.y, a1);
      a1 = fmaf(e6, xb.z, a1); a1 = fmaf(e7, xb.w, a1);
    }
    u32 v = pk(a0, a1);
    int cw = hlf * 32 + cg * 8 + p;
    if (kv == 0) KBt[(((s << 6) + cw) << 6) + l] = v;
    else         vtS[l][cg * 8 + p] = v;
  }
  if (kv == 1) {
    __syncthreads();
    int r = tid >> 2, cb = (tid & 3) * 8;
    #pragma unroll
    for (int k = 0; k < 8; ++k)
      VB[(((s << 6) + r) << 6) + hlf * 32 + cb + k] = vtS[r][cb + k];
  }
}

// ---------------- kernel 2: Q=2/wave, register-broadcast, wave-synchronous --
// grid 1024 x 256: b -> s = b>>3, qo = b&7; wave w -> queries qo*8 + 2w + t.
__global__ __launch_bounds__(256, 4) void ee_main(
    const float* __restrict__ nf, const float* __restrict__ pos,
    const float* __restrict__ w1, const float* __restrict__ b1,
    const float* __restrict__ ipb, const float* __restrict__ ob,
    const float* __restrict__ pb,
    const float* __restrict__ W2KT, const float* __restrict__ W2VT,
    const u32* __restrict__ WQB, const u32* __restrict__ OWB,
    const u32* __restrict__ PWB,
    const u32* __restrict__ KBt, const u32* __restrict__ VB,
    float* __restrict__ outp)
{
  __shared__ __align__(16) float pxS[64], pyS[64], w1xS[64], w1yS[64], b1S[64];
  __shared__ __align__(16) float scrS[4][2][4][68];  // qw (S4-S5) -> wh (S6-S7)
  __shared__ __align__(16) float atS [4][2][4][68];  // attn [w][t][hd][j]

  const int tid = threadIdx.x;
  const int s = blockIdx.x >> 3, qo = blockIdx.x & 7;
  const int w = tid >> 6, l = tid & 63;
  const int c0 = 2 * l;

  if (tid < 64) {
    float2 p = ((const float2*)pos)[(s << 6) + tid];
    pxS[tid] = p.x; pyS[tid] = p.y;
    float2 wv = ((const float2*)w1)[tid];
    w1xS[tid] = wv.x; w1yS[tid] = wv.y;
    b1S[tid] = b1[tid];
  }
  __syncthreads();
  // ---- no block barriers past here ----

  int il[2], ig[2];
  const float4* fB[2];
  #pragma unroll
  for (int t = 0; t < 2; ++t) {
    il[t] = qo * 8 + 2 * w + t;
    ig[t] = (s << 6) + il[t];
    fB[t] = (const float4*)nf +
            (size_t)__builtin_amdgcn_readfirstlane(ig[t]) * 32;  // s_load rows
  }

  // S2: q channels (c0, c0+1) per query -> REGISTERS (no LDS)
  float q0r[2], q1r[2];
  {
    float2 bq = ((const float2*)ipb)[l];
    float a0[2] = {bq.x, bq.x}, a1[2] = {bq.y, bq.y};
    const uint4* W4 = (const uint4*)WQB;
    #pragma unroll 4
    for (int m8 = 0; m8 < 16; ++m8) {
      uint4 ua = W4[c0 * 16 + m8];
      uint4 ub = W4[(c0 + 1) * 16 + m8];
      #pragma unroll
      for (int t = 0; t < 2; ++t) {
        float4 f0 = fB[t][2 * m8], f1 = fB[t][2 * m8 + 1];
        a0[t] = dot8(ua, f0, f1, a0[t]);
        a1[t] = dot8(ub, f0, f1, a1[t]);
      }
    }
    q0r[0] = a0[0]; q0r[1] = a0[1]; q1r[0] = a1[0]; q1r[1] = a1[1];
  }

  // S4: qw[t][hd][e=l] = sum_ch q[ch] * W2KT[ch][e]   (q via readlane)
  {
    float acc[2][4];
    #pragma unroll
    for (int t = 0; t < 2; ++t)
      #pragma unroll
      for (int hd = 0; hd < 4; ++hd) acc[t][hd] = 0.f;
    #pragma unroll
    for (int ch2 = 0; ch2 < 64; ++ch2) {            // channel pair 2ch2,2ch2+1
      float g0 = W2KT[(2 * ch2) * 64 + l];          // coalesced dword
      float g1 = W2KT[(2 * ch2 + 1) * 64 + l];
      const int hd = ch2 >> 4;
      #pragma unroll
      for (int t = 0; t < 2; ++t) {
        acc[t][hd] = fmaf(g0, rl(q0r[t], ch2), acc[t][hd]);
        acc[t][hd] = fmaf(g1, rl(q1r[t], ch2), acc[t][hd]);
      }
    }
    #pragma unroll
    for (int t = 0; t < 2; ++t)
      #pragma unroll
      for (int hd = 0; hd < 4; ++hd) scrS[w][t][hd][l] = acc[t][hd];
  }
  wsync();

  // S5: scores + softmax (lane = j; kb VMEM, q via readlane, qw via LDS)
  float at_[2][4];
  float pix[2], piy[2];
  {
    float pjx = pxS[l], pjy = pyS[l];
    float rx[2], ry[2];
    #pragma unroll
    for (int t = 0; t < 2; ++t) {
      pix[t] = pxS[il[t]]; piy[t] = pyS[il[t]];      // broadcast reads
      rx[t] = pjx - pix[t]; ry[t] = pjy - piy[t];
    }
    float sc[2][4];
    #pragma unroll
    for (int t = 0; t < 2; ++t)
      #pragma unroll
      for (int hd = 0; hd < 4; ++hd) sc[t][hd] = 0.f;

    const u32* kbp = KBt + (s << 12);
    #pragma unroll
    for (int m2 = 0; m2 < 32; ++m2) {                // channels 4m2..4m2+3
      u32 u0 = kbp[((2 * m2) << 6) + l];
      u32 u1 = kbp[((2 * m2 + 1) << 6) + l];
      const int hd = m2 >> 3;
      float k0 = bl(u0), k1 = bh(u0), k2 = bl(u1), k3 = bh(u1);
      #pragma unroll
      for (int t = 0; t < 2; ++t) {
        sc[t][hd] = fmaf(k0, rl(q0r[t], 2 * m2),     sc[t][hd]);
        sc[t][hd] = fmaf(k1, rl(q1r[t], 2 * m2),     sc[t][hd]);
        sc[t][hd] = fmaf(k2, rl(q0r[t], 2 * m2 + 1), sc[t][hd]);
        sc[t][hd] = fmaf(k3, rl(q1r[t], 2 * m2 + 1), sc[t][hd]);
      }
    }
    #pragma unroll 2
    for (int eb = 0; eb < 8; ++eb) {
      float4 wx0 = *(const float4*)&w1xS[8 * eb];
      float4 wx1 = *(const float4*)&w1xS[8 * eb + 4];
      float4 wy0 = *(const float4*)&w1yS[8 * eb];
      float4 wy1 = *(const float4*)&w1yS[8 * eb + 4];
      float4 bb0 = *(const float4*)&b1S[8 * eb];
      float4 bb1 = *(const float4*)&b1S[8 * eb + 4];
      #pragma unroll
      for (int t = 0; t < 2; ++t) {
        float h0 = fmaxf(0.f, fmaf(rx[t], wx0.x, fmaf(ry[t], wy0.x, bb0.x)));
        float h1 = fmaxf(0.f, fmaf(rx[t], wx0.y, fmaf(ry[t], wy0.y, bb0.y)));
        float h2 = fmaxf(0.f, fmaf(rx[t], wx0.z, fmaf(ry[t], wy0.z, bb0.z)));
        float h3 = fmaxf(0.f, fmaf(rx[t], wx0.w, fmaf(ry[t], wy0.w, bb0.w)));
        float h4 = fmaxf(0.f, fmaf(rx[t], wx1.x, fmaf(ry[t], wy1.x, bb1.x)));
        float h5 = fmaxf(0.f, fmaf(rx[t], wx1.y, fmaf(ry[t], wy1.y, bb1.y)));
        float h6 = fmaxf(0.f, fmaf(rx[t], wx1.z, fmaf(ry[t], wy1.z, bb1.z)));
        float h7 = fmaxf(0.f, fmaf(rx[t], wx1.w, fmaf(ry[t], wy1.w, bb1.w)));
        #pragma unroll
        for (int hd = 0; hd < 4; ++hd) {
          float4 g0 = *(const float4*)&scrS[w][t][hd][8 * eb];
          float4 g1 = *(const float4*)&scrS[w][t][hd][8 * eb + 4];
          float a = sc[t][hd];
          a = fmaf(g0.x, h0, a); a = fmaf(g0.y, h1, a);
          a = fmaf(g0.z, h2, a); a = fmaf(g0.w, h3, a);
          a = fmaf(g1.x, h4, a); a = fmaf(g1.y, h5, a);
          a = fmaf(g1.z, h6, a); a = fmaf(g1.w, h7, a);
          sc[t][hd] = a;
        }
      }
    }
    #pragma unroll
    for (int t = 0; t < 2; ++t) {
      #pragma unroll
      for (int hd = 0; hd < 4; ++hd) {
        float v = sc[t][hd] * SCALE;
        float m = v;
        #pragma unroll
        for (int off = 32; off > 0; off >>= 1) m = fmaxf(m, __shfl_xor(m, off));
        float p = __expf(v - m);
        float su = p;
        #pragma unroll
        for (int off = 32; off > 0; off >>= 1) su += __shfl_xor(su, off);
#if __has_builtin(__builtin_amdgcn_rcpf)
        at_[t][hd] = p * __builtin_amdgcn_rcpf(su);
#else
        at_[t][hd] = p / su;
#endif
        atS[w][t][hd][l] = at_[t][hd];
      }
    }
  }
  wsync();

  // S6: wh[t][hd][e=l] = sum_j at[t][hd][j]*hid[t][j][e]  -> scrS (qw dead)
  {
    float wx = w1xS[l], wy = w1yS[l], bb = b1S[l];
    float wh[2][4];
    #pragma unroll
    for (int t = 0; t < 2; ++t)
      #pragma unroll
      for (int hd = 0; hd < 4; ++hd) wh[t][hd] = 0.f;
    #pragma unroll 4
    for (int j4 = 0; j4 < 16; ++j4) {
      float4 px = *(const float4*)&pxS[4 * j4];
      float4 py = *(const float4*)&pyS[4 * j4];
      #pragma unroll
      for (int t = 0; t < 2; ++t) {
        float4 a0v = *(const float4*)&atS[w][t][0][4 * j4];
        float4 a1v = *(const float4*)&atS[w][t][1][4 * j4];
        float4 a2v = *(const float4*)&atS[w][t][2][4 * j4];
        float4 a3v = *(const float4*)&atS[w][t][3][4 * j4];
        float h;
        h = fmaxf(0.f, fmaf(px.x - pix[t], wx, fmaf(py.x - piy[t], wy, bb)));
        wh[t][0] = fmaf(a0v.x, h, wh[t][0]); wh[t][1] = fmaf(a1v.x, h, wh[t][1]);
        wh[t][2] = fmaf(a2v.x, h, wh[t][2]); wh[t][3] = fmaf(a3v.x, h, wh[t][3]);
        h = fmaxf(0.f, fmaf(px.y - pix[t], wx, fmaf(py.y - piy[t], wy, bb)));
        wh[t][0] = fmaf(a0v.y, h, wh[t][0]); wh[t][1] = fmaf(a1v.y, h, wh[t][1]);
        wh[t][2] = fmaf(a2v.y, h, wh[t][2]); wh[t][3] = fmaf(a3v.y, h, wh[t][3]);
        h = fmaxf(0.f, fmaf(px.z - pix[t], wx, fmaf(py.z - piy[t], wy, bb)));
        wh[t][0] = fmaf(a0v.z, h, wh[t][0]); wh[t][1] = fmaf(a1v.z, h, wh[t][1]);
        wh[t][2] = fmaf(a2v.z, h, wh[t][2]); wh[t][3] = fmaf(a3v.z, h, wh[t][3]);
        h = fmaxf(0.f, fmaf(px.w - pix[t], wx, fmaf(py.w - piy[t], wy, bb)));
        wh[t][0] = fmaf(a0v.w, h, wh[t][0]); wh[t][1] = fmaf(a1v.w, h, wh[t][1]);
        wh[t][2] = fmaf(a2v.w, h, wh[t][2]); wh[t][3] = fmaf(a3v.w, h, wh[t][3]);
      }
    }
    #pragma unroll
    for (int t = 0; t < 2; ++t)
      #pragma unroll
      for (int hd = 0; hd < 4; ++hd) scrS[w][t][hd][l] = wh[t][hd];
  }
  wsync();

  // S7: ctx channels (c0,c0+1) -> REGISTERS (head = l>>4)
  float cx0[2] = {0.f, 0.f}, cx1[2] = {0.f, 0.f};
  {
    const int hd = l >> 4;
    const float2* V2 = (const float2*)W2VT;
    const u32* vbp = VB + (s << 12);
    #pragma unroll 4
    for (int n4 = 0; n4 < 16; ++n4) {
      float2 g0 = V2[((4 * n4 + 0) << 6) + l];
      float2 g1 = V2[((4 * n4 + 1) << 6) + l];
      float2 g2 = V2[((4 * n4 + 2) << 6) + l];
      float2 g3 = V2[((4 * n4 + 3) << 6) + l];
      u32 v0 = vbp[((4 * n4 + 0) << 6) + l];
      u32 v1 = vbp[((4 * n4 + 1) << 6) + l];
      u32 v2 = vbp[((4 * n4 + 2) << 6) + l];
      u32 v3 = vbp[((4 * n4 + 3) << 6) + l];
      #pragma unroll
      for (int t = 0; t < 2; ++t) {
        float4 whv = *(const float4*)&scrS[w][t][hd][4 * n4];
        float4 atv = *(const float4*)&atS[w][t][hd][4 * n4];
        float a0 = cx0[t], a1 = cx1[t];
        a0 = fmaf(whv.x, g0.x, a0); a1 = fmaf(whv.x, g0.y, a1);
        a0 = fmaf(atv.x, bl(v0), a0); a1 = fmaf(atv.x, bh(v0), a1);
        a0 = fmaf(whv.y, g1.x, a0); a1 = fmaf(whv.y, g1.y, a1);
        a0 = fmaf(atv.y, bl(v1), a0); a1 = fmaf(atv.y, bh(v1), a1);
        a0 = fmaf(whv.z, g2.x, a0); a1 = fmaf(whv.z, g2.y, a1);
        a0 = fmaf(atv.z, bl(v2), a0); a1 = fmaf(atv.z, bh(v2), a1);
        a0 = fmaf(whv.w, g3.x, a0); a1 = fmaf(whv.w, g3.y, a1);
        a0 = fmaf(atv.w, bl(v3), a0); a1 = fmaf(atv.w, bh(v3), a1);
        cx0[t] = a0; cx1[t] = a1;
      }
    }
  }

  // S8: attn_out channels (c0,c0+1) -> REGISTERS (ctx via readlane)
  float ao0[2], ao1[2];
  {
    float2 b = ((const float2*)ob)[l];
    float a0[2] = {b.x, b.x}, a1[2] = {b.y, b.y};
    const uint4* W4 = (const uint4*)OWB;
    #pragma unroll 4
    for (int m8 = 0; m8 < 16; ++m8) {
      uint4 ua = W4[c0 * 16 + m8];
      uint4 ub = W4[(c0 + 1) * 16 + m8];
      #pragma unroll
      for (int t = 0; t < 2; ++t) {
        float x[8];
        RL8(x, cx0[t], cx1[t], 4 * m8)
        a0[t] = dot8v(ua, x, a0[t]);
        a1[t] = dot8v(ub, x, a1[t]);
      }
    }
    ao0[0] = a0[0]; ao0[1] = a0[1]; ao1[0] = a1[0]; ao1[1] = a1[1];
  }

  // S9: out = proj_w @ [feats; ao] + proj_b   (feats scalar, ao via readlane)
  {
    float2 b = ((const float2*)pb)[l];
    float a0[2] = {b.x, b.x}, a1[2] = {b.y, b.y};
    const uint4* W4 = (const uint4*)PWB;
    #pragma unroll 4
    for (int g = 0; g < 16; ++g) {
      uint4 ua = W4[c0 * 32 + g];
      uint4 ub = W4[(c0 + 1) * 32 + g];
      #pragma unroll
      for (int t = 0; t < 2; ++t) {
        float4 f0 = fB[t][2 * g], f1 = fB[t][2 * g + 1];
        a0[t] = dot8(ua, f0, f1, a0[t]);
        a1[t] = dot8(ub, f0, f1, a1[t]);
      }
    }
    #pragma unroll 4
    for (int g = 0; g < 16; ++g) {
      uint4 ua = W4[c0 * 32 + 16 + g];
      uint4 ub = W4[(c0 + 1) * 32 + 16 + g];
      #pragma unroll
      for (int t = 0; t < 2; ++t) {
        float x[8];
        RL8(x, ao0[t], ao1[t], 4 * g)
        a0[t] = dot8v(ua, x, a0[t]);
        a1[t] = dot8v(ub, x, a1[t]);
      }
    }
    #pragma unroll
    for (int t = 0; t < 2; ++t)
      ((float2*)outp)[ig[t] * 64 + l] = make_float2(a0[t], a1[t]);
  }
}

extern "C" void kernel_launch(void* const* d_in, const int* in_sizes, int n_in,
                              void* d_out, int out_size, void* d_ws, size_t ws_size,
                              hipStream_t stream) {
  (void)in_sizes; (void)n_in; (void)out_size; (void)ws_size;
  const float* nf  = (const float*)d_in[0];
  const float* pos = (const float*)d_in[1];
  const float* w1  = (const float*)d_in[2];
  const float* b1  = (const float*)d_in[3];
  const float* w2  = (const float*)d_in[4];
  const float* b2  = (const float*)d_in[5];
  const float* ipw = (const float*)d_in[6];
  const float* ipb = (const float*)d_in[7];
  const float* ow  = (const float*)d_in[8];
  const float* ob  = (const float*)d_in[9];
  const float* pw  = (const float*)d_in[10];
  const float* pb  = (const float*)d_in[11];

  char* ws = (char*)d_ws;
  float* W2KT = (float*)(ws);
  float* W2VT = (float*)(ws + (32 << 10));
  u32* WQB  = (u32*)(ws + (64 << 10));
  u32* OWB  = (u32*)(ws + (96 << 10));
  u32* PWB  = (u32*)(ws + (128 << 10));
  u32* KBt  = (u32*)(ws + (192 << 10));
  u32* VB   = (u32*)(ws + (192 << 10) + (128 * 4096 * 4));

  ee_setup<<<dim3(552), dim3(256), 0, stream>>>(nf, b2, ipw, ipb, w2, ow, pw,
                                                W2KT, W2VT, WQB, OWB, PWB, KBt, VB);
  ee_main<<<dim3(1024), dim3(256), 0, stream>>>(nf, pos, w1, b1, ipb, ob, pb,
                                                W2KT, W2VT, WQB, OWB, PWB,
                                                KBt, VB, (float*)d_out);
}